// Round 3
// baseline (1469.473 us; speedup 1.0000x reference)
//
#include <hip/hip_runtime.h>

#define N_GRAPHS 32
#define NUM_NODES 2848
#define NTOT (N_GRAPHS * NUM_NODES)   // 91136
#define NE 1000000
#define KS 3
#define TL 5
#define HID 32
#define EPSV 1e-5f
#define SCAN_B 256
#define NBLK (NTOT / SCAN_B)          // 356 (exact)
#define HSTRIDE_U 64                  // uints per bf16 H row (48 used, pad to 256B)

// ---------------- bf16 pack/unpack ----------------

__device__ __forceinline__ float2 unpk(unsigned u) {
    return make_float2(__uint_as_float(u << 16), __uint_as_float(u & 0xffff0000u));
}
__device__ __forceinline__ unsigned bf16rn(float f) {
    unsigned x = __float_as_uint(f);
    return (x + 0x7fffu + ((x >> 16) & 1u)) >> 16;
}
__device__ __forceinline__ unsigned pk(float a, float b) {
    return bf16rn(a) | (bf16rn(b) << 16);
}

// ---------------- graph preprocessing ----------------

__global__ void k_deg(const int* __restrict__ col, const float* __restrict__ w,
                      float* __restrict__ deg, int* __restrict__ indeg) {
    int e = blockIdx.x * blockDim.x + threadIdx.x;
    if (e < NE) {
        int c = col[e];
        atomicAdd(&deg[c], w[e]);
        atomicAdd(&indeg[c], 1);
    }
}

__global__ void k_dis(float* deg) {
    int i = blockIdx.x * blockDim.x + threadIdx.x;
    if (i < NTOT) {
        float d = deg[i];
        deg[i] = (d > 0.f) ? rsqrtf(d) : 0.f;
    }
}

__global__ void k_scan1(const int* __restrict__ in, int* __restrict__ bsum) {
    __shared__ int s[SCAN_B];
    int i = blockIdx.x * SCAN_B + threadIdx.x;
    s[threadIdx.x] = (i < NTOT) ? in[i] : 0;
    __syncthreads();
    for (int st = SCAN_B / 2; st >= 1; st >>= 1) {
        if (threadIdx.x < st) s[threadIdx.x] += s[threadIdx.x + st];
        __syncthreads();
    }
    if (threadIdx.x == 0) bsum[blockIdx.x] = s[0];
}

__global__ void k_scan2(int* __restrict__ bsum) {
    __shared__ int s[512];
    int tid = threadIdx.x;
    int v = (tid < NBLK) ? bsum[tid] : 0;
    s[tid] = v;
    __syncthreads();
    for (int off = 1; off < 512; off <<= 1) {
        int a = (tid >= off) ? s[tid - off] : 0;
        __syncthreads();
        s[tid] += a;
        __syncthreads();
    }
    if (tid < NBLK) bsum[tid] = s[tid] - v;   // exclusive
}

__global__ void k_scan3(const int* __restrict__ in, const int* __restrict__ bsum,
                        int* __restrict__ offs) {
    __shared__ int s[SCAN_B];
    int i = blockIdx.x * SCAN_B + threadIdx.x;
    int v = (i < NTOT) ? in[i] : 0;
    s[threadIdx.x] = v;
    __syncthreads();
    for (int off = 1; off < SCAN_B; off <<= 1) {
        int a = (threadIdx.x >= off) ? s[threadIdx.x - off] : 0;
        __syncthreads();
        s[threadIdx.x] += a;
        __syncthreads();
    }
    if (i < NTOT) offs[i] = bsum[blockIdx.x] + s[threadIdx.x] - v;
    if (i == 0) offs[NTOT] = NE;
}

__global__ void k_fill(const int* __restrict__ row, const int* __restrict__ col,
                       const float* __restrict__ w, const float* __restrict__ dis,
                       int* __restrict__ cursor, int2* __restrict__ adj) {
    int e = blockIdx.x * blockDim.x + threadIdx.x;
    if (e < NE) {
        int r = row[e], c = col[e];
        float nm = dis[r] * w[e] * dis[c];
        int p = atomicAdd(&cursor[c], 1);
        adj[p] = make_int2(r, __float_as_int(nm));
    }
}

// ---------------- ARMA F=32 kernels (bf16 H state) ----------------

// H0[n][k][f] = sum_i x[n][i] * iw[k][i][f]  (bf16 packed)
template<int FIN>
__global__ void k_init32(const float* __restrict__ x, const float* __restrict__ iw,
                         unsigned* __restrict__ H) {
    int tid = blockIdx.x * blockDim.x + threadIdx.x;   // NTOT*16 exact
    int f2 = tid & 15;
    int n = tid >> 4;
    float a00 = 0.f, a01 = 0.f, a10 = 0.f, a11 = 0.f, a20 = 0.f, a21 = 0.f;
    const float2* iw2 = (const float2*)iw;
#pragma unroll
    for (int i = 0; i < FIN; ++i) {
        float xv = x[n * FIN + i];
        float2 w0 = iw2[(0 * FIN + i) * 16 + f2];
        float2 w1 = iw2[(1 * FIN + i) * 16 + f2];
        float2 w2 = iw2[(2 * FIN + i) * 16 + f2];
        a00 += xv * w0.x; a01 += xv * w0.y;
        a10 += xv * w1.x; a11 += xv * w1.y;
        a20 += xv * w2.x; a21 += xv * w2.y;
    }
    unsigned* hn = H + (size_t)n * HSTRIDE_U;
    hn[f2]      = pk(a00, a01);
    hn[16 + f2] = pk(a10, a11);
    hn[32 + f2] = pk(a20, a21);
}

// Fused prop: relu(gather + xin@rw_t + b_t); then transform->bf16 H, or mean->fp32 out
template<int FIN, bool LAST>
__global__ __launch_bounds__(256) void k_prop32(
    const unsigned* __restrict__ H, const float* __restrict__ xin,
    const float* __restrict__ rw_t, const float* __restrict__ b_t,
    const float* __restrict__ W_t, const int* __restrict__ offs,
    const int2* __restrict__ adj, void* __restrict__ outp) {
    int tid = threadIdx.x;
    int f2 = tid & 15;
    int nl = tid >> 4;
    int node = blockIdx.x * 16 + nl;   // grid exact

    float a00, a01, a10, a11, a20, a21;
    const float2* b2p = (const float2*)b_t;
    { float2 t = b2p[0 * 16 + f2]; a00 = t.x; a01 = t.y; }
    { float2 t = b2p[1 * 16 + f2]; a10 = t.x; a11 = t.y; }
    { float2 t = b2p[2 * 16 + f2]; a20 = t.x; a21 = t.y; }
    const float2* rw2 = (const float2*)rw_t;
#pragma unroll
    for (int i = 0; i < FIN; ++i) {
        float xv = xin[node * FIN + i];
        float2 r0 = rw2[(0 * FIN + i) * 16 + f2];
        float2 r1 = rw2[(1 * FIN + i) * 16 + f2];
        float2 r2 = rw2[(2 * FIN + i) * 16 + f2];
        a00 += xv * r0.x; a01 += xv * r0.y;
        a10 += xv * r1.x; a11 += xv * r1.y;
        a20 += xv * r2.x; a21 += xv * r2.y;
    }

    int e0 = offs[node], e1 = offs[node + 1];
    int e = e0;
    for (; e + 2 <= e1; e += 2) {
        int2 ed0 = adj[e], ed1 = adj[e + 1];
        const unsigned* h0 = H + (size_t)ed0.x * HSTRIDE_U + f2;
        const unsigned* h1 = H + (size_t)ed1.x * HSTRIDE_U + f2;
        unsigned p00 = h0[0], p01 = h0[16], p02 = h0[32];
        unsigned p10 = h1[0], p11 = h1[16], p12 = h1[32];
        float w0 = __int_as_float(ed0.y), w1 = __int_as_float(ed1.y);
        float2 v;
        v = unpk(p00); a00 += w0 * v.x; a01 += w0 * v.y;
        v = unpk(p01); a10 += w0 * v.x; a11 += w0 * v.y;
        v = unpk(p02); a20 += w0 * v.x; a21 += w0 * v.y;
        v = unpk(p10); a00 += w1 * v.x; a01 += w1 * v.y;
        v = unpk(p11); a10 += w1 * v.x; a11 += w1 * v.y;
        v = unpk(p12); a20 += w1 * v.x; a21 += w1 * v.y;
    }
    if (e < e1) {
        int2 ed0 = adj[e];
        const unsigned* h0 = H + (size_t)ed0.x * HSTRIDE_U + f2;
        unsigned p00 = h0[0], p01 = h0[16], p02 = h0[32];
        float w0 = __int_as_float(ed0.y);
        float2 v;
        v = unpk(p00); a00 += w0 * v.x; a01 += w0 * v.y;
        v = unpk(p01); a10 += w0 * v.x; a11 += w0 * v.y;
        v = unpk(p02); a20 += w0 * v.x; a21 += w0 * v.y;
    }
    a00 = fmaxf(a00, 0.f); a01 = fmaxf(a01, 0.f);
    a10 = fmaxf(a10, 0.f); a11 = fmaxf(a11, 0.f);
    a20 = fmaxf(a20, 0.f); a21 = fmaxf(a21, 0.f);

    if constexpr (LAST) {
        float2 o;
        o.x = (a00 + a10 + a20) * (1.f / 3.f);
        o.y = (a01 + a11 + a21) * (1.f / 3.f);
        ((float2*)outp)[node * 16 + f2] = o;
    } else {
        __shared__ float so[16][3][33];   // pad 33: conflict-free across nl groups
        so[nl][0][2 * f2] = a00; so[nl][0][2 * f2 + 1] = a01;
        so[nl][1][2 * f2] = a10; so[nl][1][2 * f2 + 1] = a11;
        so[nl][2][2 * f2] = a20; so[nl][2][2 * f2 + 1] = a21;
        __syncthreads();
        float h00 = 0.f, h01 = 0.f, h10 = 0.f, h11 = 0.f, h20 = 0.f, h21 = 0.f;
        const float2* W2 = (const float2*)W_t;
#pragma unroll
        for (int i = 0; i < HID; ++i) {
            float s0 = so[nl][0][i], s1 = so[nl][1][i], s2 = so[nl][2][i];
            float2 w0 = W2[(0 * HID + i) * 16 + f2];
            float2 w1 = W2[(1 * HID + i) * 16 + f2];
            float2 w2 = W2[(2 * HID + i) * 16 + f2];
            h00 += s0 * w0.x; h01 += s0 * w0.y;
            h10 += s1 * w1.x; h11 += s1 * w1.y;
            h20 += s2 * w2.x; h21 += s2 * w2.y;
        }
        unsigned* hn = (unsigned*)outp + (size_t)node * HSTRIDE_U;
        hn[f2]      = pk(h00, h01);
        hn[16 + f2] = pk(h10, h11);
        hn[32 + f2] = pk(h20, h21);
    }
}

// ---------------- ARMA F=1 kernels (fp32 H, 16B rows, L2-resident) ----------------

__global__ void k_init1(const float* __restrict__ x, const float* __restrict__ iw,
                        float* __restrict__ H) {
    int n = blockIdx.x * blockDim.x + threadIdx.x;
    if (n >= NTOT) return;
    float a0 = 0.f, a1 = 0.f, a2 = 0.f;
#pragma unroll
    for (int i = 0; i < HID; ++i) {
        float xv = x[n * HID + i];
        a0 += xv * iw[0 * HID + i];
        a1 += xv * iw[1 * HID + i];
        a2 += xv * iw[2 * HID + i];
    }
    float* hn = H + (size_t)n * 4;
    hn[0] = a0; hn[1] = a1; hn[2] = a2;
}

template<bool LAST>
__global__ void k_prop1(const float* __restrict__ H, const float* __restrict__ xin,
                        const float* __restrict__ rw_t, const float* __restrict__ b_t,
                        const float* __restrict__ W_t, const int* __restrict__ offs,
                        const int2* __restrict__ adj, float* __restrict__ outp) {
    int node = blockIdx.x * blockDim.x + threadIdx.x;
    if (node >= NTOT) return;
    float a0 = b_t[0], a1 = b_t[1], a2 = b_t[2];
#pragma unroll
    for (int i = 0; i < HID; ++i) {
        float xv = xin[node * HID + i];
        a0 += xv * rw_t[0 * HID + i];
        a1 += xv * rw_t[1 * HID + i];
        a2 += xv * rw_t[2 * HID + i];
    }
    int e0 = offs[node], e1 = offs[node + 1];
    for (int e = e0; e < e1; ++e) {
        int2 ed = adj[e];
        const float* hr = H + (size_t)ed.x * 4;
        float w = __int_as_float(ed.y);
        a0 += w * hr[0]; a1 += w * hr[1]; a2 += w * hr[2];
    }
    a0 = fmaxf(a0, 0.f); a1 = fmaxf(a1, 0.f); a2 = fmaxf(a2, 0.f);
    if constexpr (LAST) {
        outp[node] = (a0 + a1 + a2) * (1.f / 3.f);
    } else {
        float* hn = outp + (size_t)node * 4;
        hn[0] = a0 * W_t[0]; hn[1] = a1 * W_t[1]; hn[2] = a2 * W_t[2];
    }
}

// ---------------- batchnorm (+relu) ----------------

__global__ void k_bnstats(const float* __restrict__ x, float* __restrict__ stats, int F) {
    __shared__ float s1[256];
    __shared__ float s2[256];
    int tid = threadIdx.x;
    int gid = blockIdx.x * blockDim.x + tid;
    int stride = gridDim.x * blockDim.x;
    int total = NTOT * F;
    float a = 0.f, b = 0.f;
    for (int i = gid; i < total; i += stride) {
        float v = x[i];
        a += v;
        b += v * v;
    }
    s1[tid] = a; s2[tid] = b;
    __syncthreads();
    for (int s = 128; s >= F; s >>= 1) {
        if (tid < s) { s1[tid] += s1[tid + s]; s2[tid] += s2[tid + s]; }
        __syncthreads();
    }
    if (tid < F) {
        atomicAdd(&stats[tid], s1[tid]);
        atomicAdd(&stats[F + tid], s2[tid]);
    }
}

__global__ void k_bnapply(float* __restrict__ x, const float* __restrict__ stats,
                          const float* __restrict__ g, const float* __restrict__ be, int F) {
    int i = blockIdx.x * blockDim.x + threadIdx.x;
    int total = NTOT * F;
    if (i >= total) return;
    int f = i % F;
    float m = stats[f] * (1.f / (float)NTOT);
    float v = stats[F + f] * (1.f / (float)NTOT) - m * m;
    float y = (x[i] - m) * rsqrtf(v + EPSV) * g[f] + be[f];
    x[i] = fmaxf(y, 0.f);
}

// ---------------- classifier + per-graph max ----------------

__global__ void k_final(const float* __restrict__ h, const float* __restrict__ cw,
                        const float* __restrict__ cb, float* __restrict__ out) {
    __shared__ float smax[256];
    int g = blockIdx.x;
    float cwv = cw[0], cbv = cb[0];
    float mx = -INFINITY;
    for (int i = threadIdx.x; i < NUM_NODES; i += blockDim.x) {
        int nidx = g * NUM_NODES + i;
        float v = h[nidx] * cwv + cbv;
        out[nidx] = v;
        mx = fmaxf(mx, v);
    }
    smax[threadIdx.x] = mx;
    __syncthreads();
    for (int s = 128; s >= 1; s >>= 1) {
        if (threadIdx.x < s) smax[threadIdx.x] = fmaxf(smax[threadIdx.x], smax[threadIdx.x + s]);
        __syncthreads();
    }
    if (threadIdx.x == 0) out[NTOT + g] = smax[0];
}

// ---------------- host launch ----------------

extern "C" void kernel_launch(void* const* d_in, const int* in_sizes, int n_in,
                              void* d_out, int out_size, void* d_ws, size_t ws_size,
                              hipStream_t stream) {
    const float* x   = (const float*)d_in[0];
    const int*   ei  = (const int*)d_in[1];
    const int*   row = ei;
    const int*   col = ei + NE;
    const float* wts = (const float*)d_in[2];
    const float* iw1 = (const float*)d_in[4];
    const float* w1  = (const float*)d_in[5];
    const float* rw1 = (const float*)d_in[6];
    const float* b1  = (const float*)d_in[7];
    const float* g1  = (const float*)d_in[8];
    const float* be1 = (const float*)d_in[9];
    const float* iw2 = (const float*)d_in[10];
    const float* w2  = (const float*)d_in[11];
    const float* rw2 = (const float*)d_in[12];
    const float* b2  = (const float*)d_in[13];
    const float* g2  = (const float*)d_in[14];
    const float* be2 = (const float*)d_in[15];
    const float* iw3 = (const float*)d_in[16];
    const float* w3  = (const float*)d_in[17];
    const float* rw3 = (const float*)d_in[18];
    const float* b3  = (const float*)d_in[19];
    const float* g3  = (const float*)d_in[20];
    const float* be3 = (const float*)d_in[21];
    const float* cw  = (const float*)d_in[22];
    const float* cb  = (const float*)d_in[23];
    float* out = (float*)d_out;

    char* p = (char*)d_ws;
    auto alloc = [&](size_t bytes) {
        char* r = p;
        p += (bytes + 255) & ~(size_t)255;
        return r;
    };
    float*    deg    = (float*)alloc((size_t)NTOT * 4);
    int*      indeg  = (int*)alloc((size_t)NTOT * 4);
    int*      bsum   = (int*)alloc((size_t)NBLK * 4);
    int*      offs   = (int*)alloc((size_t)(NTOT + 1) * 4);
    int*      cursor = (int*)alloc((size_t)NTOT * 4);
    int2*     adj    = (int2*)alloc((size_t)NE * 8);
    unsigned* HA     = (unsigned*)alloc((size_t)NTOT * HSTRIDE_U * 4);
    unsigned* HB     = (unsigned*)alloc((size_t)NTOT * HSTRIDE_U * 4);
    float*    xa     = (float*)alloc((size_t)NTOT * HID * 4);
    float*    xb     = (float*)alloc((size_t)NTOT * HID * 4);
    float*    xc     = (float*)alloc((size_t)NTOT * 4);
    float*    stats  = (float*)alloc(2 * HID * 4);
    if ((size_t)(p - (char*)d_ws) > ws_size) return;

    const int tb = 256;
    const int ebl = (NE + tb - 1) / tb;
    const int nbl = (NTOT + tb - 1) / tb;
    const int g16 = NTOT / 16;   // 5696: k_init32 / k_prop32 grids

    hipMemsetAsync(deg, 0, (size_t)NTOT * 4, stream);
    hipMemsetAsync(indeg, 0, (size_t)NTOT * 4, stream);
    k_deg<<<ebl, tb, 0, stream>>>(col, wts, deg, indeg);
    k_dis<<<nbl, tb, 0, stream>>>(deg);
    k_scan1<<<NBLK, SCAN_B, 0, stream>>>(indeg, bsum);
    k_scan2<<<1, 512, 0, stream>>>(bsum);
    k_scan3<<<NBLK, SCAN_B, 0, stream>>>(indeg, bsum, offs);
    hipMemcpyAsync(cursor, offs, (size_t)NTOT * 4, hipMemcpyDeviceToDevice, stream);
    k_fill<<<ebl, tb, 0, stream>>>(row, col, wts, deg, cursor, adj);

    // ---- layer 1: 2 -> 32 ----
    {
        constexpr int FIN = 2, F = HID;
        k_init32<FIN><<<g16, tb, 0, stream>>>(x, iw1, HA);
        const unsigned* Hc = HA; unsigned* Hn = HB;
        for (int t = 0; t < TL - 1; ++t) {
            k_prop32<FIN, false><<<g16, tb, 0, stream>>>(
                Hc, x, rw1 + (size_t)t * KS * FIN * F, b1 + (size_t)t * KS * F,
                w1 + (size_t)t * KS * F * F, offs, adj, Hn);
            const unsigned* tmp = Hc; Hc = Hn; Hn = (unsigned*)tmp;
        }
        k_prop32<FIN, true><<<g16, tb, 0, stream>>>(
            Hc, x, rw1 + (size_t)(TL - 1) * KS * FIN * F, b1 + (size_t)(TL - 1) * KS * F,
            nullptr, offs, adj, xa);
        hipMemsetAsync(stats, 0, (size_t)2 * F * 4, stream);
        k_bnstats<<<256, tb, 0, stream>>>(xa, stats, F);
        k_bnapply<<<(NTOT * F) / tb, tb, 0, stream>>>(xa, stats, g1, be1, F);
    }
    // ---- layer 2: 32 -> 32 ----
    {
        constexpr int FIN = HID, F = HID;
        k_init32<FIN><<<g16, tb, 0, stream>>>(xa, iw2, HA);
        const unsigned* Hc = HA; unsigned* Hn = HB;
        for (int t = 0; t < TL - 1; ++t) {
            k_prop32<FIN, false><<<g16, tb, 0, stream>>>(
                Hc, xa, rw2 + (size_t)t * KS * FIN * F, b2 + (size_t)t * KS * F,
                w2 + (size_t)t * KS * F * F, offs, adj, Hn);
            const unsigned* tmp = Hc; Hc = Hn; Hn = (unsigned*)tmp;
        }
        k_prop32<FIN, true><<<g16, tb, 0, stream>>>(
            Hc, xa, rw2 + (size_t)(TL - 1) * KS * FIN * F, b2 + (size_t)(TL - 1) * KS * F,
            nullptr, offs, adj, xb);
        hipMemsetAsync(stats, 0, (size_t)2 * F * 4, stream);
        k_bnstats<<<256, tb, 0, stream>>>(xb, stats, F);
        k_bnapply<<<(NTOT * F) / tb, tb, 0, stream>>>(xb, stats, g2, be2, F);
    }
    // ---- layer 3: 32 -> 1 (fp32 H, 16B rows) ----
    {
        float* HAf = (float*)HA;
        float* HBf = (float*)HB;
        k_init1<<<nbl, tb, 0, stream>>>(xb, iw3, HAf);
        const float* Hc = HAf; float* Hn = HBf;
        for (int t = 0; t < TL - 1; ++t) {
            k_prop1<false><<<nbl, tb, 0, stream>>>(
                Hc, xb, rw3 + (size_t)t * KS * HID, b3 + (size_t)t * KS,
                w3 + (size_t)t * KS, offs, adj, Hn);
            const float* tmp = Hc; Hc = Hn; Hn = (float*)tmp;
        }
        k_prop1<true><<<nbl, tb, 0, stream>>>(
            Hc, xb, rw3 + (size_t)(TL - 1) * KS * HID, b3 + (size_t)(TL - 1) * KS,
            nullptr, offs, adj, xc);
        hipMemsetAsync(stats, 0, (size_t)2 * 4, stream);
        k_bnstats<<<256, tb, 0, stream>>>(xc, stats, 1);
        k_bnapply<<<nbl, tb, 0, stream>>>(xc, stats, g3, be3, 1);
    }

    k_final<<<N_GRAPHS, 256, 0, stream>>>(xc, cw, cb, out);
}

// Round 4
// 1446.914 us; speedup vs baseline: 1.0156x; 1.0156x over previous
//
#include <hip/hip_runtime.h>

#define N_GRAPHS 32
#define NUM_NODES 2848
#define NTOT (N_GRAPHS * NUM_NODES)   // 91136
#define NE 1000000
#define KS 3
#define TL 5
#define HID 32
#define EPSV 1e-5f
#define SCAN_B 256
#define TILE_SHIFT 13                 // src tile = 8192 nodes -> 1.5MB bf16 H tile
#define NT 12                         // ceil(91136/8192)
#define NVN (NTOT * NT)               // 1093632 (multiple of 256)
#define NBLK2 (NVN / SCAN_B)          // 4272
#define HSTRIDE_U 48                  // uints per bf16 H row (192B, exactly 2 lines)

// ---------------- bf16 pack/unpack ----------------

__device__ __forceinline__ float2 unpk(unsigned u) {
    return make_float2(__uint_as_float(u << 16), __uint_as_float(u & 0xffff0000u));
}
__device__ __forceinline__ unsigned bf16rn(float f) {
    unsigned x = __float_as_uint(f);
    return (x + 0x7fffu + ((x >> 16) & 1u)) >> 16;
}
__device__ __forceinline__ unsigned pk(float a, float b) {
    return bf16rn(a) | (bf16rn(b) << 16);
}

// ---------------- graph preprocessing ----------------

// deg[c] += w ; indeg2[c*NT + tile(r)] += 1
__global__ void k_deg(const int* __restrict__ row, const int* __restrict__ col,
                      const float* __restrict__ w, float* __restrict__ deg,
                      int* __restrict__ indeg2) {
    int e = blockIdx.x * blockDim.x + threadIdx.x;
    if (e < NE) {
        int r = row[e], c = col[e];
        atomicAdd(&deg[c], w[e]);
        atomicAdd(&indeg2[c * NT + (r >> TILE_SHIFT)], 1);
    }
}

__global__ void k_dis(float* deg) {
    int i = blockIdx.x * blockDim.x + threadIdx.x;
    if (i < NTOT) {
        float d = deg[i];
        deg[i] = (d > 0.f) ? rsqrtf(d) : 0.f;
    }
}

// hierarchical exclusive scan of indeg2[NVN] -> offs2[NVN+1]
__global__ void k_scan1(const int* __restrict__ in, int* __restrict__ bsum) {
    __shared__ int s[SCAN_B];
    int i = blockIdx.x * SCAN_B + threadIdx.x;
    s[threadIdx.x] = in[i];
    __syncthreads();
    for (int st = SCAN_B / 2; st >= 1; st >>= 1) {
        if (threadIdx.x < st) s[threadIdx.x] += s[threadIdx.x + st];
        __syncthreads();
    }
    if (threadIdx.x == 0) bsum[blockIdx.x] = s[0];
}

__global__ void k_scan2(int* __restrict__ bsum) {
    __shared__ int s[1024];
    __shared__ int carry_s;
    int tid = threadIdx.x;
    if (tid == 0) carry_s = 0;
    __syncthreads();
    for (int c = 0; c < NBLK2; c += 1024) {
        int i = c + tid;
        int v = (i < NBLK2) ? bsum[i] : 0;
        s[tid] = v;
        __syncthreads();
        for (int off = 1; off < 1024; off <<= 1) {
            int a = (tid >= off) ? s[tid - off] : 0;
            __syncthreads();
            s[tid] += a;
            __syncthreads();
        }
        int incl = s[tid];
        int carry = carry_s;
        __syncthreads();
        if (i < NBLK2) bsum[i] = carry + incl - v;   // exclusive
        if (tid == 1023) carry_s = carry + incl;
        __syncthreads();
    }
}

__global__ void k_scan3(const int* __restrict__ in, const int* __restrict__ bsum,
                        int* __restrict__ offs) {
    __shared__ int s[SCAN_B];
    int i = blockIdx.x * SCAN_B + threadIdx.x;
    int v = in[i];
    s[threadIdx.x] = v;
    __syncthreads();
    for (int off = 1; off < SCAN_B; off <<= 1) {
        int a = (threadIdx.x >= off) ? s[threadIdx.x - off] : 0;
        __syncthreads();
        s[threadIdx.x] += a;
        __syncthreads();
    }
    offs[i] = bsum[blockIdx.x] + s[threadIdx.x] - v;
    if (i == 0) offs[NVN] = NE;
}

__global__ void k_fill(const int* __restrict__ row, const int* __restrict__ col,
                       const float* __restrict__ w, const float* __restrict__ dis,
                       int* __restrict__ cursor, int2* __restrict__ adj) {
    int e = blockIdx.x * blockDim.x + threadIdx.x;
    if (e < NE) {
        int r = row[e], c = col[e];
        float nm = dis[r] * w[e] * dis[c];
        int p = atomicAdd(&cursor[c * NT + (r >> TILE_SHIFT)], 1);
        adj[p] = make_int2(r, __float_as_int(nm));
    }
}

// ---------------- ARMA F=32 kernels (bf16 H state) ----------------

template<int FIN>
__global__ void k_init32(const float* __restrict__ x, const float* __restrict__ iw,
                         unsigned* __restrict__ H) {
    int tid = blockIdx.x * blockDim.x + threadIdx.x;   // NTOT*16 exact
    int f2 = tid & 15;
    int n = tid >> 4;
    float a00 = 0.f, a01 = 0.f, a10 = 0.f, a11 = 0.f, a20 = 0.f, a21 = 0.f;
    const float2* iw2 = (const float2*)iw;
#pragma unroll
    for (int i = 0; i < FIN; ++i) {
        float xv = x[n * FIN + i];
        float2 w0 = iw2[(0 * FIN + i) * 16 + f2];
        float2 w1 = iw2[(1 * FIN + i) * 16 + f2];
        float2 w2 = iw2[(2 * FIN + i) * 16 + f2];
        a00 += xv * w0.x; a01 += xv * w0.y;
        a10 += xv * w1.x; a11 += xv * w1.y;
        a20 += xv * w2.x; a21 += xv * w2.y;
    }
    unsigned* hn = H + (size_t)n * HSTRIDE_U;
    hn[f2]      = pk(a00, a01);
    hn[16 + f2] = pk(a10, a11);
    hn[32 + f2] = pk(a20, a21);
}

template<int FIN, bool LAST>
__global__ __launch_bounds__(256) void k_prop32(
    const unsigned* __restrict__ H, const float* __restrict__ xin,
    const float* __restrict__ rw_t, const float* __restrict__ b_t,
    const float* __restrict__ W_t, const int* __restrict__ offs2,
    const int2* __restrict__ adj, void* __restrict__ outp) {
    int tid = threadIdx.x;
    int f2 = tid & 15;
    int nl = tid >> 4;
    int node = blockIdx.x * 16 + nl;   // grid exact

    float a00, a01, a10, a11, a20, a21;
    const float2* b2p = (const float2*)b_t;
    { float2 t = b2p[0 * 16 + f2]; a00 = t.x; a01 = t.y; }
    { float2 t = b2p[1 * 16 + f2]; a10 = t.x; a11 = t.y; }
    { float2 t = b2p[2 * 16 + f2]; a20 = t.x; a21 = t.y; }
    const float2* rw2 = (const float2*)rw_t;
#pragma unroll
    for (int i = 0; i < FIN; ++i) {
        float xv = xin[node * FIN + i];
        float2 r0 = rw2[(0 * FIN + i) * 16 + f2];
        float2 r1 = rw2[(1 * FIN + i) * 16 + f2];
        float2 r2 = rw2[(2 * FIN + i) * 16 + f2];
        a00 += xv * r0.x; a01 += xv * r0.y;
        a10 += xv * r1.x; a11 += xv * r1.y;
        a20 += xv * r2.x; a21 += xv * r2.y;
    }

    int e0 = offs2[node * NT];
    int e1 = offs2[node * NT + NT];
    int e = e0;
    for (; e + 4 <= e1; e += 4) {
        int2 ed0 = adj[e], ed1 = adj[e + 1], ed2 = adj[e + 2], ed3 = adj[e + 3];
        const unsigned* h0 = H + (size_t)ed0.x * HSTRIDE_U + f2;
        const unsigned* h1 = H + (size_t)ed1.x * HSTRIDE_U + f2;
        const unsigned* h2 = H + (size_t)ed2.x * HSTRIDE_U + f2;
        const unsigned* h3 = H + (size_t)ed3.x * HSTRIDE_U + f2;
        unsigned p00 = h0[0], p01 = h0[16], p02 = h0[32];
        unsigned p10 = h1[0], p11 = h1[16], p12 = h1[32];
        unsigned p20 = h2[0], p21 = h2[16], p22 = h2[32];
        unsigned p30 = h3[0], p31 = h3[16], p32 = h3[32];
        float w0 = __int_as_float(ed0.y), w1 = __int_as_float(ed1.y);
        float w2 = __int_as_float(ed2.y), w3 = __int_as_float(ed3.y);
        float2 v;
        v = unpk(p00); a00 += w0 * v.x; a01 += w0 * v.y;
        v = unpk(p01); a10 += w0 * v.x; a11 += w0 * v.y;
        v = unpk(p02); a20 += w0 * v.x; a21 += w0 * v.y;
        v = unpk(p10); a00 += w1 * v.x; a01 += w1 * v.y;
        v = unpk(p11); a10 += w1 * v.x; a11 += w1 * v.y;
        v = unpk(p12); a20 += w1 * v.x; a21 += w1 * v.y;
        v = unpk(p20); a00 += w2 * v.x; a01 += w2 * v.y;
        v = unpk(p21); a10 += w2 * v.x; a11 += w2 * v.y;
        v = unpk(p22); a20 += w2 * v.x; a21 += w2 * v.y;
        v = unpk(p30); a00 += w3 * v.x; a01 += w3 * v.y;
        v = unpk(p31); a10 += w3 * v.x; a11 += w3 * v.y;
        v = unpk(p32); a20 += w3 * v.x; a21 += w3 * v.y;
    }
    for (; e < e1; ++e) {
        int2 ed0 = adj[e];
        const unsigned* h0 = H + (size_t)ed0.x * HSTRIDE_U + f2;
        unsigned p00 = h0[0], p01 = h0[16], p02 = h0[32];
        float w0 = __int_as_float(ed0.y);
        float2 v;
        v = unpk(p00); a00 += w0 * v.x; a01 += w0 * v.y;
        v = unpk(p01); a10 += w0 * v.x; a11 += w0 * v.y;
        v = unpk(p02); a20 += w0 * v.x; a21 += w0 * v.y;
    }
    a00 = fmaxf(a00, 0.f); a01 = fmaxf(a01, 0.f);
    a10 = fmaxf(a10, 0.f); a11 = fmaxf(a11, 0.f);
    a20 = fmaxf(a20, 0.f); a21 = fmaxf(a21, 0.f);

    if constexpr (LAST) {
        float2 o;
        o.x = (a00 + a10 + a20) * (1.f / 3.f);
        o.y = (a01 + a11 + a21) * (1.f / 3.f);
        ((float2*)outp)[node * 16 + f2] = o;
    } else {
        __shared__ float so[16][3][33];   // pad: conflict-free
        so[nl][0][2 * f2] = a00; so[nl][0][2 * f2 + 1] = a01;
        so[nl][1][2 * f2] = a10; so[nl][1][2 * f2 + 1] = a11;
        so[nl][2][2 * f2] = a20; so[nl][2][2 * f2 + 1] = a21;
        __syncthreads();
        float h00 = 0.f, h01 = 0.f, h10 = 0.f, h11 = 0.f, h20 = 0.f, h21 = 0.f;
        const float2* W2 = (const float2*)W_t;
#pragma unroll
        for (int i = 0; i < HID; ++i) {
            float s0 = so[nl][0][i], s1 = so[nl][1][i], s2 = so[nl][2][i];
            float2 w0 = W2[(0 * HID + i) * 16 + f2];
            float2 w1 = W2[(1 * HID + i) * 16 + f2];
            float2 w2 = W2[(2 * HID + i) * 16 + f2];
            h00 += s0 * w0.x; h01 += s0 * w0.y;
            h10 += s1 * w1.x; h11 += s1 * w1.y;
            h20 += s2 * w2.x; h21 += s2 * w2.y;
        }
        unsigned* hn = (unsigned*)outp + (size_t)node * HSTRIDE_U;
        hn[f2]      = pk(h00, h01);
        hn[16 + f2] = pk(h10, h11);
        hn[32 + f2] = pk(h20, h21);
    }
}

// ---------------- ARMA F=1 kernels (fp32 H, float4 rows) ----------------

__global__ void k_init1(const float* __restrict__ x, const float* __restrict__ iw,
                        float4* __restrict__ H) {
    int n = blockIdx.x * blockDim.x + threadIdx.x;
    if (n >= NTOT) return;
    float a0 = 0.f, a1 = 0.f, a2 = 0.f;
#pragma unroll
    for (int i = 0; i < HID; ++i) {
        float xv = x[n * HID + i];
        a0 += xv * iw[0 * HID + i];
        a1 += xv * iw[1 * HID + i];
        a2 += xv * iw[2 * HID + i];
    }
    H[n] = make_float4(a0, a1, a2, 0.f);
}

template<bool LAST>
__global__ void k_prop1(const float4* __restrict__ H, const float* __restrict__ xin,
                        const float* __restrict__ rw_t, const float* __restrict__ b_t,
                        const float* __restrict__ W_t, const int* __restrict__ offs2,
                        const int2* __restrict__ adj, float* __restrict__ outp) {
    int node = blockIdx.x * blockDim.x + threadIdx.x;
    if (node >= NTOT) return;
    float a0 = b_t[0], a1 = b_t[1], a2 = b_t[2];
#pragma unroll
    for (int i = 0; i < HID; ++i) {
        float xv = xin[node * HID + i];
        a0 += xv * rw_t[0 * HID + i];
        a1 += xv * rw_t[1 * HID + i];
        a2 += xv * rw_t[2 * HID + i];
    }
    int e0 = offs2[node * NT];
    int e1 = offs2[node * NT + NT];
    int e = e0;
    for (; e + 4 <= e1; e += 4) {
        int2 ed0 = adj[e], ed1 = adj[e + 1], ed2 = adj[e + 2], ed3 = adj[e + 3];
        float4 h0 = H[ed0.x], h1 = H[ed1.x], h2 = H[ed2.x], h3 = H[ed3.x];
        float w0 = __int_as_float(ed0.y), w1 = __int_as_float(ed1.y);
        float w2 = __int_as_float(ed2.y), w3 = __int_as_float(ed3.y);
        a0 += w0 * h0.x; a1 += w0 * h0.y; a2 += w0 * h0.z;
        a0 += w1 * h1.x; a1 += w1 * h1.y; a2 += w1 * h1.z;
        a0 += w2 * h2.x; a1 += w2 * h2.y; a2 += w2 * h2.z;
        a0 += w3 * h3.x; a1 += w3 * h3.y; a2 += w3 * h3.z;
    }
    for (; e < e1; ++e) {
        int2 ed = adj[e];
        float4 h = H[ed.x];
        float w = __int_as_float(ed.y);
        a0 += w * h.x; a1 += w * h.y; a2 += w * h.z;
    }
    a0 = fmaxf(a0, 0.f); a1 = fmaxf(a1, 0.f); a2 = fmaxf(a2, 0.f);
    if constexpr (LAST) {
        outp[node] = (a0 + a1 + a2) * (1.f / 3.f);
    } else {
        ((float4*)outp)[node] = make_float4(a0 * W_t[0], a1 * W_t[1], a2 * W_t[2], 0.f);
    }
}

// ---------------- batchnorm (+relu) ----------------

__global__ void k_bnstats(const float* __restrict__ x, float* __restrict__ stats, int F) {
    __shared__ float s1[256];
    __shared__ float s2[256];
    int tid = threadIdx.x;
    int gid = blockIdx.x * blockDim.x + tid;
    int stride = gridDim.x * blockDim.x;
    int total = NTOT * F;
    float a = 0.f, b = 0.f;
    for (int i = gid; i < total; i += stride) {
        float v = x[i];
        a += v;
        b += v * v;
    }
    s1[tid] = a; s2[tid] = b;
    __syncthreads();
    for (int s = 128; s >= F; s >>= 1) {
        if (tid < s) { s1[tid] += s1[tid + s]; s2[tid] += s2[tid + s]; }
        __syncthreads();
    }
    if (tid < F) {
        atomicAdd(&stats[tid], s1[tid]);
        atomicAdd(&stats[F + tid], s2[tid]);
    }
}

__global__ void k_bnapply(float* __restrict__ x, const float* __restrict__ stats,
                          const float* __restrict__ g, const float* __restrict__ be, int F) {
    int i = blockIdx.x * blockDim.x + threadIdx.x;
    int total = NTOT * F;
    if (i >= total) return;
    int f = i % F;
    float m = stats[f] * (1.f / (float)NTOT);
    float v = stats[F + f] * (1.f / (float)NTOT) - m * m;
    float y = (x[i] - m) * rsqrtf(v + EPSV) * g[f] + be[f];
    x[i] = fmaxf(y, 0.f);
}

// ---------------- classifier + per-graph max ----------------

__global__ void k_final(const float* __restrict__ h, const float* __restrict__ cw,
                        const float* __restrict__ cb, float* __restrict__ out) {
    __shared__ float smax[256];
    int g = blockIdx.x;
    float cwv = cw[0], cbv = cb[0];
    float mx = -INFINITY;
    for (int i = threadIdx.x; i < NUM_NODES; i += blockDim.x) {
        int nidx = g * NUM_NODES + i;
        float v = h[nidx] * cwv + cbv;
        out[nidx] = v;
        mx = fmaxf(mx, v);
    }
    smax[threadIdx.x] = mx;
    __syncthreads();
    for (int s = 128; s >= 1; s >>= 1) {
        if (threadIdx.x < s) smax[threadIdx.x] = fmaxf(smax[threadIdx.x], smax[threadIdx.x + s]);
        __syncthreads();
    }
    if (threadIdx.x == 0) out[NTOT + g] = smax[0];
}

// ---------------- host launch ----------------

extern "C" void kernel_launch(void* const* d_in, const int* in_sizes, int n_in,
                              void* d_out, int out_size, void* d_ws, size_t ws_size,
                              hipStream_t stream) {
    const float* x   = (const float*)d_in[0];
    const int*   ei  = (const int*)d_in[1];
    const int*   row = ei;
    const int*   col = ei + NE;
    const float* wts = (const float*)d_in[2];
    const float* iw1 = (const float*)d_in[4];
    const float* w1  = (const float*)d_in[5];
    const float* rw1 = (const float*)d_in[6];
    const float* b1  = (const float*)d_in[7];
    const float* g1  = (const float*)d_in[8];
    const float* be1 = (const float*)d_in[9];
    const float* iw2 = (const float*)d_in[10];
    const float* w2  = (const float*)d_in[11];
    const float* rw2 = (const float*)d_in[12];
    const float* b2  = (const float*)d_in[13];
    const float* g2  = (const float*)d_in[14];
    const float* be2 = (const float*)d_in[15];
    const float* iw3 = (const float*)d_in[16];
    const float* w3  = (const float*)d_in[17];
    const float* rw3 = (const float*)d_in[18];
    const float* b3  = (const float*)d_in[19];
    const float* g3  = (const float*)d_in[20];
    const float* be3 = (const float*)d_in[21];
    const float* cw  = (const float*)d_in[22];
    const float* cb  = (const float*)d_in[23];
    float* out = (float*)d_out;

    char* p = (char*)d_ws;
    auto alloc = [&](size_t bytes) {
        char* r = p;
        p += (bytes + 255) & ~(size_t)255;
        return r;
    };
    float*    deg    = (float*)alloc((size_t)NTOT * 4);
    int*      indeg2 = (int*)alloc((size_t)NVN * 4);
    int*      bsum   = (int*)alloc((size_t)NBLK2 * 4);
    int*      offs2  = (int*)alloc((size_t)(NVN + 1) * 4);
    int*      cursor = (int*)alloc((size_t)NVN * 4);
    int2*     adj    = (int2*)alloc((size_t)NE * 8);
    unsigned* HA     = (unsigned*)alloc((size_t)NTOT * HSTRIDE_U * 4);
    unsigned* HB     = (unsigned*)alloc((size_t)NTOT * HSTRIDE_U * 4);
    float*    xa     = (float*)alloc((size_t)NTOT * HID * 4);
    float*    xb     = (float*)alloc((size_t)NTOT * HID * 4);
    float*    xc     = (float*)alloc((size_t)NTOT * 4);
    float*    stats  = (float*)alloc(3 * 2 * HID * 4);
    if ((size_t)(p - (char*)d_ws) > ws_size) return;

    const int tb = 256;
    const int ebl = (NE + tb - 1) / tb;
    const int nbl = (NTOT + tb - 1) / tb;
    const int g16 = NTOT / 16;

    // zero deg + indeg2 (adjacent allocs) and all bn stats in two memsets
    hipMemsetAsync(deg, 0, (size_t)((char*)bsum - (char*)deg), stream);
    hipMemsetAsync(stats, 0, (size_t)3 * 2 * HID * 4, stream);

    k_deg<<<ebl, tb, 0, stream>>>(row, col, wts, deg, indeg2);
    k_dis<<<nbl, tb, 0, stream>>>(deg);
    k_scan1<<<NBLK2, SCAN_B, 0, stream>>>(indeg2, bsum);
    k_scan2<<<1, 1024, 0, stream>>>(bsum);
    k_scan3<<<NBLK2, SCAN_B, 0, stream>>>(indeg2, bsum, offs2);
    hipMemcpyAsync(cursor, offs2, (size_t)NVN * 4, hipMemcpyDeviceToDevice, stream);
    k_fill<<<ebl, tb, 0, stream>>>(row, col, wts, deg, cursor, adj);

    // ---- layer 1: 2 -> 32 ----
    {
        constexpr int FIN = 2, F = HID;
        k_init32<FIN><<<g16, tb, 0, stream>>>(x, iw1, HA);
        const unsigned* Hc = HA; unsigned* Hn = HB;
        for (int t = 0; t < TL - 1; ++t) {
            k_prop32<FIN, false><<<g16, tb, 0, stream>>>(
                Hc, x, rw1 + (size_t)t * KS * FIN * F, b1 + (size_t)t * KS * F,
                w1 + (size_t)t * KS * F * F, offs2, adj, Hn);
            const unsigned* tmp = Hc; Hc = Hn; Hn = (unsigned*)tmp;
        }
        k_prop32<FIN, true><<<g16, tb, 0, stream>>>(
            Hc, x, rw1 + (size_t)(TL - 1) * KS * FIN * F, b1 + (size_t)(TL - 1) * KS * F,
            nullptr, offs2, adj, xa);
        k_bnstats<<<256, tb, 0, stream>>>(xa, stats, F);
        k_bnapply<<<(NTOT * F) / tb, tb, 0, stream>>>(xa, stats, g1, be1, F);
    }
    // ---- layer 2: 32 -> 32 ----
    {
        constexpr int FIN = HID, F = HID;
        k_init32<FIN><<<g16, tb, 0, stream>>>(xa, iw2, HA);
        const unsigned* Hc = HA; unsigned* Hn = HB;
        for (int t = 0; t < TL - 1; ++t) {
            k_prop32<FIN, false><<<g16, tb, 0, stream>>>(
                Hc, xa, rw2 + (size_t)t * KS * FIN * F, b2 + (size_t)t * KS * F,
                w2 + (size_t)t * KS * F * F, offs2, adj, Hn);
            const unsigned* tmp = Hc; Hc = Hn; Hn = (unsigned*)tmp;
        }
        k_prop32<FIN, true><<<g16, tb, 0, stream>>>(
            Hc, xa, rw2 + (size_t)(TL - 1) * KS * FIN * F, b2 + (size_t)(TL - 1) * KS * F,
            nullptr, offs2, adj, xb);
        k_bnstats<<<256, tb, 0, stream>>>(xb, stats + 2 * HID, F);
        k_bnapply<<<(NTOT * F) / tb, tb, 0, stream>>>(xb, stats + 2 * HID, g2, be2, F);
    }
    // ---- layer 3: 32 -> 1 ----
    {
        float4* HAf = (float4*)HA;
        float4* HBf = (float4*)HB;
        k_init1<<<nbl, tb, 0, stream>>>(xb, iw3, HAf);
        const float4* Hc = HAf; float4* Hn = HBf;
        for (int t = 0; t < TL - 1; ++t) {
            k_prop1<false><<<nbl, tb, 0, stream>>>(
                Hc, xb, rw3 + (size_t)t * KS * HID, b3 + (size_t)t * KS,
                w3 + (size_t)t * KS, offs2, adj, (float*)Hn);
            const float4* tmp = Hc; Hc = Hn; Hn = (float4*)tmp;
        }
        k_prop1<true><<<nbl, tb, 0, stream>>>(
            Hc, xb, rw3 + (size_t)(TL - 1) * KS * HID, b3 + (size_t)(TL - 1) * KS,
            nullptr, offs2, adj, xc);
        k_bnstats<<<256, tb, 0, stream>>>(xc, stats + 4 * HID, 1);
        k_bnapply<<<nbl, tb, 0, stream>>>(xc, stats + 4 * HID, g3, be3, 1);
    }

    k_final<<<N_GRAPHS, 256, 0, stream>>>(xc, cw, cb, out);
}